// Round 14
// baseline (167.866 us; speedup 1.0000x reference)
//
#include <hip/hip_runtime.h>

// Problem constants: B=32, C_IN=64, C_OUT=128, K=3, H=W=128
#define BATCH 32
#define CIN   64
#define COUT  128
#define HW    128
#define OW    126            // H-K+1
#define IMG4  508032         // float4s per batch-image of out (128*126*126/4)
#define WTN   (32 * 576 * 4) // repacked weight floats: [ocGroup4][ic*9+t][4]

typedef float f4 __attribute__((ext_vector_type(4)));

// ---- Kernel 1 (frozen from R11): xs = sum_b x[b]; also repacks w -> wt ----
__global__ __launch_bounds__(256) void k_bsum(const float* __restrict__ x,
                                              float* __restrict__ xs,
                                              const float* __restrict__ w,
                                              float* __restrict__ wt) {
    const int i = blockIdx.x * blockDim.x + threadIdx.x;   // over 262144 f4s
    const f4* __restrict__ x4 = (const f4*)x;
    const size_t s4 = CIN * HW * HW / 4;                   // 262144 f4 per batch
    f4 a0 = __builtin_nontemporal_load(&x4[i]);
    f4 a1 = __builtin_nontemporal_load(&x4[s4 + i]);
    f4 a2 = __builtin_nontemporal_load(&x4[2 * s4 + i]);
    f4 a3 = __builtin_nontemporal_load(&x4[3 * s4 + i]);
    #pragma unroll
    for (int b = 4; b < BATCH; b += 4) {
        a0 += __builtin_nontemporal_load(&x4[(size_t)b * s4 + i]);
        a1 += __builtin_nontemporal_load(&x4[(size_t)(b + 1) * s4 + i]);
        a2 += __builtin_nontemporal_load(&x4[(size_t)(b + 2) * s4 + i]);
        a3 += __builtin_nontemporal_load(&x4[(size_t)(b + 3) * s4 + i]);
    }
    ((f4*)xs)[i] = (a0 + a1) + (a2 + a3);

    // Weight repack: wt[g*2304 + r*4 + o] = w[(g*4+o)*576 + r]
    if (blockIdx.x < WTN / 256) {
        const int idx = blockIdx.x * 256 + threadIdx.x;
        const int o = idx & 3;
        const int r = (idx >> 2) % 576;
        const int g = idx / 2304;
        wt[idx] = w[(g * 4 + o) * 576 + r];
    }
}

// ---- Kernel 2 (frozen from R11): conv(xs, wt) + bias -> out batch 0 ----
// MEASUREMENT ROUND: launched TWICE (idempotent) to expose conv duration as
// (total - 121.6). Everything byte-identical to R11.
#define OCT 16             // out channels per block

__global__ __launch_bounds__(256, 2) void k_conv(const float* __restrict__ xs,
                                                 const float* __restrict__ wt,
                                                 const float* __restrict__ bias,
                                                 float* __restrict__ out) {
    const int tid  = threadIdx.x;
    const int tile = blockIdx.x;                 // 0..63
    const int ocg  = blockIdx.y;                 // 0..7
    const int row0 = (tile >> 2) * 8;            // 0..120
    const int col0 = (tile & 3) * 32;            // 0,32,64,96
    const int oc0  = ocg * OCT;

    const int tx = tid & 7;
    const int ty = (tid >> 3) & 7;
    const int og = tid >> 6;                     // 0..3 (wave-uniform)

    const int irow = row0 + ty;                  // output row; input rows irow+ky
    const int icol = col0 + tx * 4;              // output col base
    const bool tail = (icol + 5) < HW;           // cols icol+4..5 loadable

    // Uniform weight base for this wave's 4 output channels
    const int ogl = __builtin_amdgcn_readfirstlane(ocg * 4 + og);
    const float* __restrict__ wp = wt + (size_t)ogl * 2304;  // [ic*9+t][4]

    float acc[4][4] = {};                        // [oc][px]

    float bufA[18], bufB[18];                    // x values, [ky*6 + j]
    const float* xbase = &xs[(size_t)irow * HW + icol];

    auto loadx = [&](float* buf, int ic) {
        const float* p = xbase + (size_t)ic * (HW * HW);
        #pragma unroll
        for (int ky = 0; ky < 3; ++ky) {
            const int gr = irow + ky;
            if (gr < HW) {
                const float4 xa = *(const float4*)(p + ky * HW);
                buf[ky * 6 + 0] = xa.x; buf[ky * 6 + 1] = xa.y;
                buf[ky * 6 + 2] = xa.z; buf[ky * 6 + 3] = xa.w;
                if (tail) {
                    const float2 xt = *(const float2*)(p + ky * HW + 4);
                    buf[ky * 6 + 4] = xt.x; buf[ky * 6 + 5] = xt.y;
                } else { buf[ky * 6 + 4] = 0.f; buf[ky * 6 + 5] = 0.f; }
            } else {
                #pragma unroll
                for (int j = 0; j < 6; ++j) buf[ky * 6 + j] = 0.f;
            }
        }
    };

    auto fmas = [&](const float* buf, int ic) {
        #pragma unroll
        for (int ky = 0; ky < 3; ++ky) {
            #pragma unroll
            for (int kx = 0; kx < 3; ++kx) {
                // uniform address -> s_load_dwordx4 into SGPRs
                const f4 wv = *(const f4*)(wp + (ic * 9 + ky * 3 + kx) * 4);
                const float wf[4] = {wv.x, wv.y, wv.z, wv.w};
                #pragma unroll
                for (int o = 0; o < 4; ++o)
                    #pragma unroll
                    for (int p = 0; p < 4; ++p)
                        acc[o][p] = fmaf(wf[o], buf[ky * 6 + kx + p], acc[o][p]);
            }
        }
    };

    loadx(bufA, 0);
    for (int ic = 0; ic < CIN; ic += 2) {        // software pipeline, depth 1
        loadx(bufB, ic + 1);
        fmas(bufA, ic);
        if (ic + 2 < CIN) loadx(bufA, ic + 2);
        fmas(bufB, ic + 1);
    }

    // Bias + write batch 0 only (row pitch 126f -> float2 stores)
    if (irow < OW) {
        #pragma unroll
        for (int o = 0; o < 4; ++o) {
            const int oc = oc0 + og * 4 + o;
            const float bv = bias[oc];
            const float r0 = acc[o][0] + bv, r1 = acc[o][1] + bv;
            const float r2 = acc[o][2] + bv, r3 = acc[o][3] + bv;
            float* op = &out[((size_t)oc * OW + irow) * OW + icol];
            if (icol + 4 <= OW) {
                ((float2*)op)[0] = make_float2(r0, r1);
                ((float2*)op)[1] = make_float2(r2, r3);
            } else {                              // icol == 124: 2 cols left
                ((float2*)op)[0] = make_float2(r0, r1);
            }
        }
    }
}

// ---- Kernel 3 (frozen from R11/R6 form): fan-out broadcast ----
__global__ __launch_bounds__(256) void k_bcast(float* __restrict__ out) {
    f4* __restrict__ o4 = (f4*)out;
    const int r0 = blockIdx.x * 512 + threadIdx.x;
    const int r1 = r0 + 256;
    const bool ok0 = r0 < IMG4;
    const bool ok1 = r1 < IMG4;
    f4 v0 = {}; f4 v1 = {};
    if (ok0) v0 = o4[r0];
    if (ok1) v1 = o4[r1];
    #pragma unroll
    for (int b = 1; b < BATCH; ++b) {
        const size_t base = (size_t)b * IMG4;
        if (ok0) o4[base + r0] = v0;
        if (ok1) o4[base + r1] = v1;
    }
}

extern "C" void kernel_launch(void* const* d_in, const int* in_sizes, int n_in,
                              void* d_out, int out_size, void* d_ws, size_t ws_size,
                              hipStream_t stream) {
    const float* x    = (const float*)d_in[0];   // [32,64,128,128]
    const float* w    = (const float*)d_in[1];   // [128,64,3,3]
    const float* bias = (const float*)d_in[2];   // [128,1,1]
    float* out = (float*)d_out;                  // [32,128,126,126]
    float* wt  = (float*)d_ws;                   // repacked weights (288 KB)
    float* xs  = wt + WTN;                       // [64,128,128] (4 MB), 16B-aligned

    k_bsum<<<dim3(CIN * HW * HW / 4 / 256), dim3(256), 0, stream>>>(x, xs, w, wt);
    k_conv<<<dim3(64, 8), dim3(256), 0, stream>>>(xs, wt, bias, out);
    k_conv<<<dim3(64, 8), dim3(256), 0, stream>>>(xs, wt, bias, out);  // 2nd: timing probe
    k_bcast<<<dim3((IMG4 + 511) / 512), dim3(256), 0, stream>>>(out);
}

// Round 15
// 140.743 us; speedup vs baseline: 1.1927x; 1.1927x over previous
//
#include <hip/hip_runtime.h>

// Problem constants: B=32, C_IN=64, C_OUT=128, K=3, H=W=128
#define BATCH 32
#define CIN   64
#define COUT  128
#define HW    128
#define OW    126            // H-K+1
#define IMG4  508032         // float4s per batch-image of out (128*126*126/4)
#define WTN   (64 * 576 * 2) // repacked weight floats: [ocPair][ic*9+t][2]

typedef float f4 __attribute__((ext_vector_type(4)));
typedef float f2 __attribute__((ext_vector_type(2)));

// ---- Kernel 1 (logic frozen from R11; repack layout now oc-PAIRS) ----
__global__ __launch_bounds__(256) void k_bsum(const float* __restrict__ x,
                                              float* __restrict__ xs,
                                              const float* __restrict__ w,
                                              float* __restrict__ wt) {
    const int i = blockIdx.x * blockDim.x + threadIdx.x;   // over 262144 f4s
    const f4* __restrict__ x4 = (const f4*)x;
    const size_t s4 = CIN * HW * HW / 4;                   // 262144 f4 per batch
    f4 a0 = __builtin_nontemporal_load(&x4[i]);
    f4 a1 = __builtin_nontemporal_load(&x4[s4 + i]);
    f4 a2 = __builtin_nontemporal_load(&x4[2 * s4 + i]);
    f4 a3 = __builtin_nontemporal_load(&x4[3 * s4 + i]);
    #pragma unroll
    for (int b = 4; b < BATCH; b += 4) {
        a0 += __builtin_nontemporal_load(&x4[(size_t)b * s4 + i]);
        a1 += __builtin_nontemporal_load(&x4[(size_t)(b + 1) * s4 + i]);
        a2 += __builtin_nontemporal_load(&x4[(size_t)(b + 2) * s4 + i]);
        a3 += __builtin_nontemporal_load(&x4[(size_t)(b + 3) * s4 + i]);
    }
    ((f4*)xs)[i] = (a0 + a1) + (a2 + a3);

    // Weight repack: wt[(g2*576 + r)*2 + o] = w[(g2*2+o)*576 + r], g2 = oc pair
    if (blockIdx.x < WTN / 256) {
        const int idx = blockIdx.x * 256 + threadIdx.x;
        const int o  = idx & 1;
        const int r  = (idx >> 1) % 576;
        const int g2 = idx / 1152;
        wt[idx] = w[(g2 * 2 + o) * 576 + r];
    }
}

// ---- Kernel 2 (THE lever this round): conv -> out batch 0, 4 blocks/CU ----
// Same engine (x direct from L2/L3, scalar-pipe weights, depth-1 pipeline),
// but OCT=8 / grid (64,16) = 1024 blocks -> 4 blocks/CU = 4 waves/SIMD, so
// TLP hides the per-ic load latency that 2 waves/SIMD could not.
#define OCT 8              // out channels per block

__global__ __launch_bounds__(256, 4) void k_conv(const float* __restrict__ xs,
                                                 const float* __restrict__ wt,
                                                 const float* __restrict__ bias,
                                                 float* __restrict__ out) {
    const int tid  = threadIdx.x;
    const int tile = blockIdx.x;                 // 0..63
    const int ocg  = blockIdx.y;                 // 0..15
    const int row0 = (tile >> 2) * 8;            // 0..120
    const int col0 = (tile & 3) * 32;            // 0,32,64,96
    const int oc0  = ocg * OCT;

    const int tx = tid & 7;
    const int ty = (tid >> 3) & 7;
    const int og = tid >> 6;                     // 0..3 (wave-uniform)

    const int irow = row0 + ty;                  // output row; input rows irow+ky
    const int icol = col0 + tx * 4;              // output col base
    const bool tail = (icol + 5) < HW;           // cols icol+4..5 loadable

    // Uniform weight base for this wave's oc PAIR (scalar pipe: s_load_dwordx2)
    const int ogl = __builtin_amdgcn_readfirstlane(ocg * 4 + og);   // 0..63
    const float* __restrict__ wp = wt + (size_t)ogl * 1152;         // [ic*9+t][2]

    float acc[2][4] = {};                        // [oc][px]

    float bufA[18], bufB[18];                    // x values, [ky*6 + j]
    const float* xbase = &xs[(size_t)irow * HW + icol];

    auto loadx = [&](float* buf, int ic) {
        const float* p = xbase + (size_t)ic * (HW * HW);
        #pragma unroll
        for (int ky = 0; ky < 3; ++ky) {
            const int gr = irow + ky;
            if (gr < HW) {
                const float4 xa = *(const float4*)(p + ky * HW);
                buf[ky * 6 + 0] = xa.x; buf[ky * 6 + 1] = xa.y;
                buf[ky * 6 + 2] = xa.z; buf[ky * 6 + 3] = xa.w;
                if (tail) {
                    const float2 xt = *(const float2*)(p + ky * HW + 4);
                    buf[ky * 6 + 4] = xt.x; buf[ky * 6 + 5] = xt.y;
                } else { buf[ky * 6 + 4] = 0.f; buf[ky * 6 + 5] = 0.f; }
            } else {
                #pragma unroll
                for (int j = 0; j < 6; ++j) buf[ky * 6 + j] = 0.f;
            }
        }
    };

    auto fmas = [&](const float* buf, int ic) {
        #pragma unroll
        for (int ky = 0; ky < 3; ++ky) {
            #pragma unroll
            for (int kx = 0; kx < 3; ++kx) {
                // uniform address -> s_load_dwordx2 into SGPRs
                const f2 wv = *(const f2*)(wp + (ic * 9 + ky * 3 + kx) * 2);
                const float wf[2] = {wv.x, wv.y};
                #pragma unroll
                for (int o = 0; o < 2; ++o)
                    #pragma unroll
                    for (int p = 0; p < 4; ++p)
                        acc[o][p] = fmaf(wf[o], buf[ky * 6 + kx + p], acc[o][p]);
            }
        }
    };

    loadx(bufA, 0);
    for (int ic = 0; ic < CIN; ic += 2) {        // software pipeline, depth 1
        loadx(bufB, ic + 1);
        fmas(bufA, ic);
        if (ic + 2 < CIN) loadx(bufA, ic + 2);
        fmas(bufB, ic + 1);
    }

    // Bias + write batch 0 only (row pitch 126f -> float2 stores)
    if (irow < OW) {
        #pragma unroll
        for (int o = 0; o < 2; ++o) {
            const int oc = oc0 + og * 2 + o;
            const float bv = bias[oc];
            const float r0 = acc[o][0] + bv, r1 = acc[o][1] + bv;
            const float r2 = acc[o][2] + bv, r3 = acc[o][3] + bv;
            float* op = &out[((size_t)oc * OW + irow) * OW + icol];
            if (icol + 4 <= OW) {
                ((float2*)op)[0] = make_float2(r0, r1);
                ((float2*)op)[1] = make_float2(r2, r3);
            } else {                              // icol == 124: 2 cols left
                ((float2*)op)[0] = make_float2(r0, r1);
            }
        }
    }
}

// ---- Kernel 3 (frozen, at write roofline): fan-out broadcast ----
__global__ __launch_bounds__(256) void k_bcast(float* __restrict__ out) {
    f4* __restrict__ o4 = (f4*)out;
    const int r0 = blockIdx.x * 512 + threadIdx.x;
    const int r1 = r0 + 256;
    const bool ok0 = r0 < IMG4;
    const bool ok1 = r1 < IMG4;
    f4 v0 = {}; f4 v1 = {};
    if (ok0) v0 = o4[r0];
    if (ok1) v1 = o4[r1];
    #pragma unroll
    for (int b = 1; b < BATCH; ++b) {
        const size_t base = (size_t)b * IMG4;
        if (ok0) o4[base + r0] = v0;
        if (ok1) o4[base + r1] = v1;
    }
}

extern "C" void kernel_launch(void* const* d_in, const int* in_sizes, int n_in,
                              void* d_out, int out_size, void* d_ws, size_t ws_size,
                              hipStream_t stream) {
    const float* x    = (const float*)d_in[0];   // [32,64,128,128]
    const float* w    = (const float*)d_in[1];   // [128,64,3,3]
    const float* bias = (const float*)d_in[2];   // [128,1,1]
    float* out = (float*)d_out;                  // [32,128,126,126]
    float* wt  = (float*)d_ws;                   // repacked weights (576 KB)
    float* xs  = wt + WTN;                       // [64,128,128] (4 MB), 16B-aligned

    k_bsum<<<dim3(CIN * HW * HW / 4 / 256), dim3(256), 0, stream>>>(x, xs, w, wt);
    k_conv<<<dim3(64, 16), dim3(256), 0, stream>>>(xs, wt, bias, out);
    k_bcast<<<dim3((IMG4 + 511) / 512), dim3(256), 0, stream>>>(out);
}

// Round 16
// 112.752 us; speedup vs baseline: 1.4888x; 1.2482x over previous
//
#include <hip/hip_runtime.h>

// Problem constants: B=32, C_IN=64, C_OUT=128, K=3, H=W=128
#define BATCH 32
#define CIN   64
#define COUT  128
#define HW    128
#define OW    126            // H-K+1
#define IMG4  508032         // float4s per batch-image of out (128*126*126/4)

typedef float f4 __attribute__((ext_vector_type(4)));
typedef float f32x4 __attribute__((ext_vector_type(4)));
typedef short s8v __attribute__((ext_vector_type(8)));   // bf16x8 MFMA fragment
typedef unsigned short u16;

__device__ inline u16 bf16_rne(float v) {                // round-to-nearest-even
    unsigned b = __float_as_uint(v);
    unsigned r = b + 0x7FFF + ((b >> 16) & 1);
    return (u16)(r >> 16);
}
__device__ inline float bf16_f(u16 h) { return __uint_as_float(((unsigned)h) << 16); }

// ---- Kernel 1: xs = sum_b x[b] -> channel-last bf16 hi/lo; + weight repack ----
// xh/xl: [h*128+w][64ic] u16 (2 MB each). wh/wl: [(t*128+oc)*64+ic] u16 (144 KB each).
__global__ __launch_bounds__(256) void k_bsum(const float* __restrict__ x,
                                              const float* __restrict__ w,
                                              u16* __restrict__ xh,
                                              u16* __restrict__ xl,
                                              u16* __restrict__ wh,
                                              u16* __restrict__ wl) {
    const int i = blockIdx.x * blockDim.x + threadIdx.x;   // over 262144 f4s
    const f4* __restrict__ x4 = (const f4*)x;
    const size_t s4 = CIN * HW * HW / 4;                   // 262144 f4 per batch
    f4 a0 = __builtin_nontemporal_load(&x4[i]);
    f4 a1 = __builtin_nontemporal_load(&x4[s4 + i]);
    f4 a2 = __builtin_nontemporal_load(&x4[2 * s4 + i]);
    f4 a3 = __builtin_nontemporal_load(&x4[3 * s4 + i]);
    #pragma unroll
    for (int b = 4; b < BATCH; b += 4) {
        a0 += __builtin_nontemporal_load(&x4[(size_t)b * s4 + i]);
        a1 += __builtin_nontemporal_load(&x4[(size_t)(b + 1) * s4 + i]);
        a2 += __builtin_nontemporal_load(&x4[(size_t)(b + 2) * s4 + i]);
        a3 += __builtin_nontemporal_load(&x4[(size_t)(b + 3) * s4 + i]);
    }
    const f4 s = (a0 + a1) + (a2 + a3);

    // i indexes [c][hw/4]: c = i>>12, hw = (i&4095)*4. Write channel-last.
    const int c  = i >> 12;
    const int hw = (i & 4095) << 2;
    #pragma unroll
    for (int j = 0; j < 4; ++j) {
        const float v = s[j];
        const u16 h = bf16_rne(v);
        const int o = (hw + j) * CIN + c;
        xh[o] = h;
        xl[o] = bf16_rne(v - bf16_f(h));
    }

    // Weight repack+split: idx = (t*128+oc)*64+ic <- w[(oc*64+ic)*9 + t]
    if (blockIdx.x < 288) {
        const int idx = blockIdx.x * 256 + threadIdx.x;    // 0..73727
        const int ic = idx & 63;
        const int oc = (idx >> 6) & 127;
        const int t  = idx >> 13;
        const float v = w[(oc * 64 + ic) * 9 + t];
        const u16 h = bf16_rne(v);
        wh[idx] = h;
        wl[idx] = bf16_rne(v - bf16_f(h));
    }
}

// ---- Kernel 2: implicit-GEMM conv via bf16 MFMA (hi/lo split) -> out batch 0 ----
// Wave tile: 32 oc x 32 px (2x2 fragments of 16x16), K = 64 ic (2 x K32),
// 9 taps accumulate into the same acc. Block = 4 waves = all 128 oc for one
// (row, 32-col) strip -> B fragments shared via L1. Grid (126 rows, 4 strips).
// Fragment rule (guide §3): lane l: A row / B col = l&15; k = (l>>4)*8 + j,
// 8 consecutive k = one short8. C/D: col = l&15, row = (l>>4)*4 + reg.
__global__ __launch_bounds__(256) void k_conv(const u16* __restrict__ xh,
                                              const u16* __restrict__ xl,
                                              const u16* __restrict__ wh,
                                              const u16* __restrict__ wl,
                                              const float* __restrict__ bias,
                                              float* __restrict__ out) {
    const int tid  = threadIdx.x;
    const int l    = tid & 63;
    const int ocb  = (tid >> 6) * 32;       // wave -> 32 output channels
    const int row  = blockIdx.x;            // 0..125
    const int col0 = blockIdx.y * 32;       // 0,32,64,96
    const int n = l & 15;
    const int g = l >> 4;

    f32x4 acc[2][2] = {};                   // [om][on]

    #pragma unroll
    for (int kb = 0; kb < 2; ++kb) {
        const int icoff = kb * 32 + g * 8;
        #pragma unroll
        for (int t = 0; t < 9; ++t) {
            const int ky = t / 3, kx = t % 3;
            const int r  = row + ky;                         // <= 127, in-bounds
            const int c0 = min(col0 + kx + n, 127);          // clamp: junk cols masked on store
            const int c1 = min(col0 + kx + 16 + n, 127);
            const s8v bh0 = *(const s8v*)(xh + (r * 128 + c0) * 64 + icoff);
            const s8v bl0 = *(const s8v*)(xl + (r * 128 + c0) * 64 + icoff);
            const s8v bh1 = *(const s8v*)(xh + (r * 128 + c1) * 64 + icoff);
            const s8v bl1 = *(const s8v*)(xl + (r * 128 + c1) * 64 + icoff);
            const int wb0 = (t * 128 + ocb + n) * 64 + icoff;
            const s8v ah0 = *(const s8v*)(wh + wb0);
            const s8v al0 = *(const s8v*)(wl + wb0);
            const s8v ah1 = *(const s8v*)(wh + wb0 + 16 * 64);
            const s8v al1 = *(const s8v*)(wl + wb0 + 16 * 64);
            // hi*hi + hi*lo + lo*hi for each of the 4 fragment tiles
            acc[0][0] = __builtin_amdgcn_mfma_f32_16x16x32_bf16(ah0, bh0, acc[0][0], 0, 0, 0);
            acc[0][0] = __builtin_amdgcn_mfma_f32_16x16x32_bf16(ah0, bl0, acc[0][0], 0, 0, 0);
            acc[0][0] = __builtin_amdgcn_mfma_f32_16x16x32_bf16(al0, bh0, acc[0][0], 0, 0, 0);
            acc[0][1] = __builtin_amdgcn_mfma_f32_16x16x32_bf16(ah0, bh1, acc[0][1], 0, 0, 0);
            acc[0][1] = __builtin_amdgcn_mfma_f32_16x16x32_bf16(ah0, bl1, acc[0][1], 0, 0, 0);
            acc[0][1] = __builtin_amdgcn_mfma_f32_16x16x32_bf16(al0, bh1, acc[0][1], 0, 0, 0);
            acc[1][0] = __builtin_amdgcn_mfma_f32_16x16x32_bf16(ah1, bh0, acc[1][0], 0, 0, 0);
            acc[1][0] = __builtin_amdgcn_mfma_f32_16x16x32_bf16(ah1, bl0, acc[1][0], 0, 0, 0);
            acc[1][0] = __builtin_amdgcn_mfma_f32_16x16x32_bf16(al1, bh0, acc[1][0], 0, 0, 0);
            acc[1][1] = __builtin_amdgcn_mfma_f32_16x16x32_bf16(ah1, bh1, acc[1][1], 0, 0, 0);
            acc[1][1] = __builtin_amdgcn_mfma_f32_16x16x32_bf16(ah1, bl1, acc[1][1], 0, 0, 0);
            acc[1][1] = __builtin_amdgcn_mfma_f32_16x16x32_bf16(al1, bh1, acc[1][1], 0, 0, 0);
        }
    }

    // Epilogue: D col = l&15 (pixel), row = g*4 + j (oc within 16-tile)
    #pragma unroll
    for (int om = 0; om < 2; ++om) {
        #pragma unroll
        for (int j = 0; j < 4; ++j) {
            const int oc = ocb + om * 16 + g * 4 + j;
            const float bv = bias[oc];
            #pragma unroll
            for (int on = 0; on < 2; ++on) {
                const int col = col0 + on * 16 + n;
                if (col < OW)
                    out[((size_t)oc * OW + row) * OW + col] = acc[om][on][j] + bv;
            }
        }
    }
}

// ---- Kernel 3 (frozen, at write roofline): fan-out broadcast ----
__global__ __launch_bounds__(256) void k_bcast(float* __restrict__ out) {
    f4* __restrict__ o4 = (f4*)out;
    const int r0 = blockIdx.x * 512 + threadIdx.x;
    const int r1 = r0 + 256;
    const bool ok0 = r0 < IMG4;
    const bool ok1 = r1 < IMG4;
    f4 v0 = {}; f4 v1 = {};
    if (ok0) v0 = o4[r0];
    if (ok1) v1 = o4[r1];
    #pragma unroll
    for (int b = 1; b < BATCH; ++b) {
        const size_t base = (size_t)b * IMG4;
        if (ok0) o4[base + r0] = v0;
        if (ok1) o4[base + r1] = v1;
    }
}

extern "C" void kernel_launch(void* const* d_in, const int* in_sizes, int n_in,
                              void* d_out, int out_size, void* d_ws, size_t ws_size,
                              hipStream_t stream) {
    const float* x    = (const float*)d_in[0];   // [32,64,128,128]
    const float* w    = (const float*)d_in[1];   // [128,64,3,3]
    const float* bias = (const float*)d_in[2];   // [128,1,1]
    float* out = (float*)d_out;                  // [32,128,126,126]

    u16* xh = (u16*)d_ws;                        // 1,048,576 elems (2 MB)
    u16* xl = xh + 1048576;                      // 2 MB
    u16* wh = xl + 1048576;                      // 73,728 elems (144 KB)
    u16* wl = wh + 73728;                        // 144 KB   (total ~4.3 MB <= ws)

    k_bsum<<<dim3(CIN * HW * HW / 4 / 256), dim3(256), 0, stream>>>(x, w, xh, xl, wh, wl);
    k_conv<<<dim3(OW, 4), dim3(256), 0, stream>>>(xh, xl, wh, wl, bias, out);
    k_bcast<<<dim3((IMG4 + 511) / 512), dim3(256), 0, stream>>>(out);
}

// Round 17
// 91.465 us; speedup vs baseline: 1.8353x; 1.2327x over previous
//
#include <hip/hip_runtime.h>

// Problem constants: B=32, C_IN=64, C_OUT=128, K=3, H=W=128
#define BATCH 32
#define CIN   64
#define COUT  128
#define HW    128
#define OW    126            // H-K+1
#define IMG4  508032         // float4s per batch-image of out (128*126*126/4)

typedef float f4 __attribute__((ext_vector_type(4)));
typedef float f32x4 __attribute__((ext_vector_type(4)));
typedef short s8v __attribute__((ext_vector_type(8)));   // bf16x8 MFMA fragment
typedef unsigned short u16;

__device__ inline u16 bf16_rne(float v) {                // round-to-nearest-even
    unsigned b = __float_as_uint(v);
    unsigned r = b + 0x7FFF + ((b >> 16) & 1);
    return (u16)(r >> 16);
}
__device__ inline float bf16_f(u16 h) { return __uint_as_float(((unsigned)h) << 16); }

// ---- Kernel 1: xs = sum_b x[b] -> TILED channel-last bf16 hi/lo via LDS transpose ----
// Output layout: xh/xl as u16[4 cb][16384 hw][16 ic]  (2 MB each).
// Block: 16 ic (cb = blockIdx.y) x 128 hw (hw0 = blockIdx.x*128). Grid (128,4) = 512.
// Reads coalesced (512B half-wave runs); stores fully coalesced u32x4 per thread.
__global__ __launch_bounds__(256) void k_bsum(const float* __restrict__ x,
                                              const float* __restrict__ w,
                                              u16* __restrict__ xh,
                                              u16* __restrict__ xl,
                                              u16* __restrict__ wh,
                                              u16* __restrict__ wl) {
    __shared__ unsigned lds[128 * 17];            // packed (hi | lo<<16), pitch 17

    const int t     = threadIdx.x;
    const int hw0   = blockIdx.x * 128;
    const int cb    = blockIdx.y;                 // 0..3 -> ic0 = cb*16
    const int f4i   = t & 31;                     // f4 index over the 128-hw tile
    const int chalf = t >> 5;                     // 0..7

    const f4* __restrict__ x4 = (const f4*)x;
    const int rb = cb * 16 + chalf;               // first of 2 c-rows (other +8)
    const int hb = (hw0 >> 2) + f4i;              // f4 offset within a c-row

    f4 acc0 = {0.f, 0.f, 0.f, 0.f};
    f4 acc1 = {0.f, 0.f, 0.f, 0.f};
    #pragma unroll 4
    for (int b = 0; b < BATCH; ++b) {
        const size_t base = (size_t)b * 262144;
        acc0 += __builtin_nontemporal_load(&x4[base + (rb    ) * 4096 + hb]);
        acc1 += __builtin_nontemporal_load(&x4[base + (rb + 8) * 4096 + hb]);
    }

    // LDS[hw][c]: c = chalf (+8), hw = f4i*4+j
    #pragma unroll
    for (int j = 0; j < 4; ++j) {
        {
            const float v = acc0[j];
            const u16 h = bf16_rne(v);
            const u16 lo = bf16_rne(v - bf16_f(h));
            lds[(f4i * 4 + j) * 17 + chalf] = (unsigned)h | ((unsigned)lo << 16);
        }
        {
            const float v = acc1[j];
            const u16 h = bf16_rne(v);
            const u16 lo = bf16_rne(v - bf16_f(h));
            lds[(f4i * 4 + j) * 17 + chalf + 8] = (unsigned)h | ((unsigned)lo << 16);
        }
    }
    __syncthreads();

    // Coalesced write-out: 1024 hi-u32 + 1024 lo-u32 per block, 4+4 per thread.
    unsigned* __restrict__ xhu = (unsigned*)xh;
    unsigned* __restrict__ xlu = (unsigned*)xl;
    const int base = cb * 131072 + hw0 * 8;       // u32 index: tile 16384*16/2 per cb
    #pragma unroll
    for (int k = 0; k < 4; ++k) {
        const int l  = t * 4 + k;                 // 0..1023
        const int hw = l >> 3;
        const int wi = l & 7;
        const unsigned e0 = lds[hw * 17 + 2 * wi];
        const unsigned e1 = lds[hw * 17 + 2 * wi + 1];
        xhu[base + l] = (e0 & 0xFFFFu) | (e1 << 16);
        xlu[base + l] = (e0 >> 16) | (e1 & 0xFFFF0000u);
    }

    // Weight repack+split: idx = (t*128+oc)*64+ic <- w[(oc*64+ic)*9 + t]
    const int bid = blockIdx.y * 128 + blockIdx.x;
    if (bid < 288) {
        const int idx = bid * 256 + t;            // 0..73727
        const int ic = idx & 63;
        const int oc = (idx >> 6) & 127;
        const int tp = idx >> 13;
        const float v = w[(oc * 64 + ic) * 9 + tp];
        const u16 h = bf16_rne(v);
        wh[idx] = h;
        wl[idx] = bf16_rne(v - bf16_f(h));
    }
}

// ---- Kernel 2: implicit-GEMM conv via bf16 MFMA (hi/lo split) -> out batch 0 ----
// Identical engine to R16; only the B-fragment address uses the tiled layout:
// xh[cb][hw][16ic], cb = kb*2 + (g>>1), off = (g&1)*8.
__global__ __launch_bounds__(256) void k_conv(const u16* __restrict__ xh,
                                              const u16* __restrict__ xl,
                                              const u16* __restrict__ wh,
                                              const u16* __restrict__ wl,
                                              const float* __restrict__ bias,
                                              float* __restrict__ out) {
    const int tid  = threadIdx.x;
    const int l    = tid & 63;
    const int ocb  = (tid >> 6) * 32;       // wave -> 32 output channels
    const int row  = blockIdx.x;            // 0..125
    const int col0 = blockIdx.y * 32;       // 0,32,64,96
    const int n = l & 15;
    const int g = l >> 4;

    f32x4 acc[2][2] = {};                   // [om][on]

    #pragma unroll
    for (int kb = 0; kb < 2; ++kb) {
        const int icoff = kb * 32 + g * 8;
        const size_t tb = (size_t)(kb * 2 + (g >> 1)) * 262144;  // tile base (u16)
        const int off = (g & 1) * 8;
        #pragma unroll
        for (int t = 0; t < 9; ++t) {
            const int ky = t / 3, kx = t % 3;
            const int r  = row + ky;                         // <= 127, in-bounds
            const int c0 = min(col0 + kx + n, 127);          // clamp: junk masked on store
            const int c1 = min(col0 + kx + 16 + n, 127);
            const s8v bh0 = *(const s8v*)(xh + tb + (r * 128 + c0) * 16 + off);
            const s8v bl0 = *(const s8v*)(xl + tb + (r * 128 + c0) * 16 + off);
            const s8v bh1 = *(const s8v*)(xh + tb + (r * 128 + c1) * 16 + off);
            const s8v bl1 = *(const s8v*)(xl + tb + (r * 128 + c1) * 16 + off);
            const int wb0 = (t * 128 + ocb + n) * 64 + icoff;
            const s8v ah0 = *(const s8v*)(wh + wb0);
            const s8v al0 = *(const s8v*)(wl + wb0);
            const s8v ah1 = *(const s8v*)(wh + wb0 + 16 * 64);
            const s8v al1 = *(const s8v*)(wl + wb0 + 16 * 64);
            // hi*hi + hi*lo + lo*hi for each of the 4 fragment tiles
            acc[0][0] = __builtin_amdgcn_mfma_f32_16x16x32_bf16(ah0, bh0, acc[0][0], 0, 0, 0);
            acc[0][0] = __builtin_amdgcn_mfma_f32_16x16x32_bf16(ah0, bl0, acc[0][0], 0, 0, 0);
            acc[0][0] = __builtin_amdgcn_mfma_f32_16x16x32_bf16(al0, bh0, acc[0][0], 0, 0, 0);
            acc[0][1] = __builtin_amdgcn_mfma_f32_16x16x32_bf16(ah0, bh1, acc[0][1], 0, 0, 0);
            acc[0][1] = __builtin_amdgcn_mfma_f32_16x16x32_bf16(ah0, bl1, acc[0][1], 0, 0, 0);
            acc[0][1] = __builtin_amdgcn_mfma_f32_16x16x32_bf16(al0, bh1, acc[0][1], 0, 0, 0);
            acc[1][0] = __builtin_amdgcn_mfma_f32_16x16x32_bf16(ah1, bh0, acc[1][0], 0, 0, 0);
            acc[1][0] = __builtin_amdgcn_mfma_f32_16x16x32_bf16(ah1, bl0, acc[1][0], 0, 0, 0);
            acc[1][0] = __builtin_amdgcn_mfma_f32_16x16x32_bf16(al1, bh0, acc[1][0], 0, 0, 0);
            acc[1][1] = __builtin_amdgcn_mfma_f32_16x16x32_bf16(ah1, bh1, acc[1][1], 0, 0, 0);
            acc[1][1] = __builtin_amdgcn_mfma_f32_16x16x32_bf16(ah1, bl1, acc[1][1], 0, 0, 0);
            acc[1][1] = __builtin_amdgcn_mfma_f32_16x16x32_bf16(al1, bh1, acc[1][1], 0, 0, 0);
        }
    }

    // Epilogue: D col = l&15 (pixel), row = g*4 + j (oc within 16-tile)
    #pragma unroll
    for (int om = 0; om < 2; ++om) {
        #pragma unroll
        for (int j = 0; j < 4; ++j) {
            const int oc = ocb + om * 16 + g * 4 + j;
            const float bv = bias[oc];
            #pragma unroll
            for (int on = 0; on < 2; ++on) {
                const int col = col0 + on * 16 + n;
                if (col < OW)
                    out[((size_t)oc * OW + row) * OW + col] = acc[om][on][j] + bv;
            }
        }
    }
}

// ---- Kernel 3 (frozen, at write roofline): fan-out broadcast ----
__global__ __launch_bounds__(256) void k_bcast(float* __restrict__ out) {
    f4* __restrict__ o4 = (f4*)out;
    const int r0 = blockIdx.x * 512 + threadIdx.x;
    const int r1 = r0 + 256;
    const bool ok0 = r0 < IMG4;
    const bool ok1 = r1 < IMG4;
    f4 v0 = {}; f4 v1 = {};
    if (ok0) v0 = o4[r0];
    if (ok1) v1 = o4[r1];
    #pragma unroll
    for (int b = 1; b < BATCH; ++b) {
        const size_t base = (size_t)b * IMG4;
        if (ok0) o4[base + r0] = v0;
        if (ok1) o4[base + r1] = v1;
    }
}

extern "C" void kernel_launch(void* const* d_in, const int* in_sizes, int n_in,
                              void* d_out, int out_size, void* d_ws, size_t ws_size,
                              hipStream_t stream) {
    const float* x    = (const float*)d_in[0];   // [32,64,128,128]
    const float* w    = (const float*)d_in[1];   // [128,64,3,3]
    const float* bias = (const float*)d_in[2];   // [128,1,1]
    float* out = (float*)d_out;                  // [32,128,126,126]

    u16* xh = (u16*)d_ws;                        // 1,048,576 elems (2 MB)
    u16* xl = xh + 1048576;                      // 2 MB
    u16* wh = xl + 1048576;                      // 73,728 elems (144 KB)
    u16* wl = wh + 73728;                        // 144 KB   (total ~4.3 MB <= ws)

    k_bsum<<<dim3(128, 4), dim3(256), 0, stream>>>(x, w, xh, xl, wh, wl);
    k_conv<<<dim3(OW, 4), dim3(256), 0, stream>>>(xh, xl, wh, wl, bias, out);
    k_bcast<<<dim3((IMG4 + 511) / 512), dim3(256), 0, stream>>>(out);
}